// Round 7
// baseline (528.673 us; speedup 1.0000x reference)
//
#include <hip/hip_runtime.h>

#define NB   16
#define SQL  2048
#define SKL  2048
#define DKL  64
#define DVL  64
#define NE   (NB * SQL * DKL)   /* 2,097,152 elems per tensor */

typedef __attribute__((ext_vector_type(8))) short short8;
typedef __attribute__((ext_vector_type(4))) short s16x4;
typedef __attribute__((ext_vector_type(4))) float f32x4;
typedef __attribute__((ext_vector_type(4))) int   i32x4;
typedef __attribute__((ext_vector_type(4))) unsigned u32x4;

#define SCALE_LOG2E 0.1803368801111204f  /* (1/sqrt(64)) * log2(e) */
#define EXP2F(x) __builtin_amdgcn_exp2f(x)
#define MFMA32(a,b,c) __builtin_amdgcn_mfma_f32_16x16x32_bf16((a),(b),(c),0,0,0)
#define SBAR() __builtin_amdgcn_sched_barrier(0)

__device__ __forceinline__ short f2bf(float x) {  // rne f32 -> bf16 bits
    unsigned u = __builtin_bit_cast(unsigned, x);
    u = (u + 0x7fffu + ((u >> 16) & 1u)) >> 16;
    return (short)u;
}
__device__ __forceinline__ float bf2f(short s) {
    return __builtin_bit_cast(float, ((unsigned)(unsigned short)s) << 16);
}

// pack 8 f32 -> 8 bf16 (RNE) via v_cvt_pk_bf16_f32
__device__ __forceinline__ short8 pk8(f32x4 a, f32x4 b) {
    unsigned w0, w1, w2, w3;
    asm("v_cvt_pk_bf16_f32 %0, %1, %2" : "=v"(w0) : "v"(a[0]), "v"(a[1]));
    asm("v_cvt_pk_bf16_f32 %0, %1, %2" : "=v"(w1) : "v"(a[2]), "v"(a[3]));
    asm("v_cvt_pk_bf16_f32 %0, %1, %2" : "=v"(w2) : "v"(b[0]), "v"(b[1]));
    asm("v_cvt_pk_bf16_f32 %0, %1, %2" : "=v"(w3) : "v"(b[2]), "v"(b[3]));
    u32x4 t = {w0, w1, w2, w3};
    return __builtin_bit_cast(short8, t);
}

// ---------- prep: split Q,K into bf16 hi/lo ----------
__global__ __launch_bounds__(256)
void prep(const float* __restrict__ Q, const float* __restrict__ K,
          short* __restrict__ ws)
{
    short* qhi = ws;
    short* qlo = ws + (size_t)NE;
    short* khi = ws + (size_t)2 * NE;
    short* klo = ws + (size_t)3 * NE;

    size_t i4 = ((size_t)blockIdx.x * 256 + threadIdx.x) * 4;
    if (i4 >= NE) return;

    f32x4 q = *(const f32x4*)(Q + i4);
    f32x4 k = *(const f32x4*)(K + i4);
    s16x4 qh, ql, kh, kl;
    #pragma unroll
    for (int j = 0; j < 4; j++) {
        qh[j] = f2bf(q[j]);  ql[j] = f2bf(q[j] - bf2f(qh[j]));
        kh[j] = f2bf(k[j]);  kl[j] = f2bf(k[j] - bf2f(kh[j]));
    }
    *(s16x4*)(qhi + i4) = qh;
    *(s16x4*)(qlo + i4) = ql;
    *(s16x4*)(khi + i4) = kh;
    *(s16x4*)(klo + i4) = kl;
}

// ---------- vtrans: V fp32 [b][k][v] -> bf16 Vt, MFMA-slot-tiled ----------
// Vt[v][t*32 + quad*8 + jj] = V[t*32 + quad*4 + (jj&3) + 16*(jj>>2)][v]
// so a 16B load at (v*SKL + kb + quad*8) is the B-fragment matching the
// packed-P A-fragment slot order: ONE mfma_16x16x32 per v-tile per 32 keys.
__global__ __launch_bounds__(256)
void vtrans(const float* __restrict__ V, short* __restrict__ vt)
{
    __shared__ short st[64][72];          // 64x64 tile, padded stride
    const int b  = blockIdx.x >> 5;       // 32 k-tiles (of 64) per batch
    const int kt = blockIdx.x & 31;
    const int t  = threadIdx.x;

    const int kr = t >> 2;                // 0..63  (k row within tile)
    const int c0 = (t & 3) * 16;          // v col chunk
    const float* vsrc = V + ((size_t)(b * SKL) + kt * 64 + kr) * DVL + c0;
    #pragma unroll
    for (int j = 0; j < 4; j++) {
        f32x4 x = *(const f32x4*)(vsrc + j * 4);
        #pragma unroll
        for (int i = 0; i < 4; i++) st[kr][c0 + j * 4 + i] = f2bf(x[i]);
    }
    __syncthreads();

    const int vr = t >> 2;                // v row of output
    const int cc = (t & 3) * 16;          // 16-elem chunk within 64 keys
    short* dst = vt + (size_t)b * DVL * SKL + (size_t)vr * SKL + kt * 64 + cc;
    short o[16];
    #pragma unroll
    for (int m = 0; m < 16; m++) {
        int kk = cc + m;
        int tb = kk >> 5;
        int w5 = kk & 31;
        int qd = w5 >> 3;
        int jj = w5 & 7;
        int kl = tb * 32 + qd * 4 + (jj & 3) + ((jj >> 2) << 4);
        o[m] = st[kl][vr];
    }
    *(short8*)(dst)     = *(short8*)(o);
    *(short8*)(dst + 8) = *(short8*)(o + 8);
}

// load the 8 K hi/lo tiles + 4 V tiles for a 32-key block into register set P
#define LOADKV(P, kb) {                                                 \
    size_t o0 = (size_t)((kb) + l15) * DKL + quad * 8;                  \
    size_t o1 = o0 + (size_t)16 * DKL;                                  \
    P##h0l = *(const short8*)(khi + o0);                                \
    P##h0h = *(const short8*)(khi + o0 + 32);                           \
    P##h1l = *(const short8*)(khi + o1);                                \
    P##h1h = *(const short8*)(khi + o1 + 32);                           \
    P##l0l = *(const short8*)(klo + o0);                                \
    P##l0h = *(const short8*)(klo + o0 + 32);                           \
    P##l1l = *(const short8*)(klo + o1);                                \
    P##l1h = *(const short8*)(klo + o1 + 32);                           \
    const short* vrow = vtg + (kb) + quad * 8;                          \
    P##v0 = *(const short8*)(vrow + (size_t)(0 * 16 + l15) * SKL);      \
    P##v1 = *(const short8*)(vrow + (size_t)(1 * 16 + l15) * SKL);      \
    P##v2 = *(const short8*)(vrow + (size_t)(2 * 16 + l15) * SKL);      \
    P##v3 = *(const short8*)(vrow + (size_t)(3 * 16 + l15) * SKL);      \
}

// one 32-key step: QK (split-bf16), unnormalized P' = exp2(s*scale + bias),
// accumulate lsum + PV, store P' fp32 to attn (normalized later by `norm`)
#define STEP(P, kb) {                                                   \
    i32x4 m0 = *(const i32x4*)(mk + (kb) + quad * 4);                   \
    i32x4 m1 = *(const i32x4*)(mk + (kb) + 16 + quad * 4);              \
    f32x4 z = {0.f, 0.f, 0.f, 0.f};                                     \
    f32x4 sA0 = MFMA32(P##h0l, qa0h, z);                                \
    sA0 = MFMA32(P##l0l, qa0h, sA0);                                    \
    sA0 = MFMA32(P##h0l, qa0l, sA0);                                    \
    f32x4 sB0 = MFMA32(P##h0h, qa1h, z);                                \
    sB0 = MFMA32(P##l0h, qa1h, sB0);                                    \
    sB0 = MFMA32(P##h0h, qa1l, sB0);                                    \
    f32x4 sA1 = MFMA32(P##h1l, qa0h, z);                                \
    sA1 = MFMA32(P##l1l, qa0h, sA1);                                    \
    sA1 = MFMA32(P##h1l, qa0l, sA1);                                    \
    f32x4 sB1 = MFMA32(P##h1h, qa1h, z);                                \
    sB1 = MFMA32(P##l1h, qa1h, sB1);                                    \
    sB1 = MFMA32(P##h1h, qa1l, sB1);                                    \
    f32x4 p0, p1;                                                       \
    _Pragma("unroll")                                                   \
    for (int r = 0; r < 4; r++) {                                       \
        p0[r] = EXP2F(fmaf(sA0[r] + sB0[r], SCALE_LOG2E, m0[r] ? 0.f : -1e9f)); \
        p1[r] = EXP2F(fmaf(sA1[r] + sB1[r], SCALE_LOG2E, m1[r] ? 0.f : -1e9f)); \
        lsum += p0[r] + p1[r];                                          \
    }                                                                   \
    short8 pa = pk8(p0, p1);                                            \
    acc0 = MFMA32(pa, P##v0, acc0);                                     \
    acc1 = MFMA32(pa, P##v1, acc1);                                     \
    acc2 = MFMA32(pa, P##v2, acc2);                                     \
    acc3 = MFMA32(pa, P##v3, acc3);                                     \
    float* arow = attn + (size_t)(b * SQL + qbase + l15) * SKL + (kb) + quad * 4; \
    *(f32x4*)arow        = p0;                                          \
    *(f32x4*)(arow + 16) = p1;                                          \
}

// Single-sweep fused attention: block = 16 q-rows, 4 waves x 512-key quarters.
// Swapped QK keeps P lane-local. PV accumulates UNNORMALIZED; out scaled by
// 1/sum in epilogue; attn holds P' (norm kernel rescales it afterward).
// Pipeline enforced with sched_barrier(0): the 12 loads of the NEXT step are
// issued, then a scheduling fence stops LLVM from sinking them into/past the
// current STEP (round-6 failure: VGPR=60-68 proves the scheduler serialized
// every load at ~430cy L2 latency -> ~9.5K cy/iter). With the fence, waits
// land after a full STEP of compute and 12 latencies overlap.
__global__ __launch_bounds__(256, 2)
void attn_fwd(const short* __restrict__ ws, const int* __restrict__ mask,
              float* __restrict__ out, float* __restrict__ attn)
{
    __shared__ __align__(16) char smem[16384 + 256];
    f32x4* s_acc = (f32x4*)smem;                 // vt-major: [vt][w*64+lane] (16 KB)
    float* s_red = (float*)(smem + 16384);       // 4 waves x 16 row-sums

    const int tid  = threadIdx.x;
    const int w    = tid >> 6;                   // wave = k-quarter
    const int lane = tid & 63;
    const int l15  = tid & 15;
    const int quad = (tid & 63) >> 4;

    // bijective XCD swizzle: 2048 blocks, 256-block chunks per XCD
    const int bid = blockIdx.x;
    const int swz = (bid & 7) * ((NB * SQL / 16) >> 3) + (bid >> 3);
    const int b     = swz >> 7;
    const int qbase = (swz & 127) * 16;

    const int k0 = w * (SKL / 4);

    const short* qhi = ws + (size_t)(b * SQL + qbase) * DKL;
    const short* qlo = qhi + (size_t)NE;
    const short* khi = ws + (size_t)2 * NE + (size_t)b * SKL * DKL;
    const short* klo = khi + (size_t)NE;
    const short* vtg = ws + (size_t)4 * NE + (size_t)b * DVL * SKL;
    const int*   mk  = mask + b * SKL;

    // Q fragments (B-operand of swapped QK: lane l15 = q, quad = d-chunk)
    short8 qa0h = *(const short8*)(qhi + (size_t)l15 * DKL + quad * 8);
    short8 qa1h = *(const short8*)(qhi + (size_t)l15 * DKL + 32 + quad * 8);
    short8 qa0l = *(const short8*)(qlo + (size_t)l15 * DKL + quad * 8);
    short8 qa1l = *(const short8*)(qlo + (size_t)l15 * DKL + 32 + quad * 8);

    f32x4 acc0 = {0.f,0.f,0.f,0.f}, acc1 = acc0, acc2 = acc0, acc3 = acc0;
    float lsum = 0.f;

    short8 Ah0l, Ah0h, Ah1l, Ah1h, Al0l, Al0h, Al1l, Al1h, Av0, Av1, Av2, Av3;
    short8 Bh0l, Bh0h, Bh1l, Bh1h, Bl0l, Bl0h, Bl1l, Bl1h, Bv0, Bv1, Bv2, Bv3;

    LOADKV(A, k0);
    for (int it = 0; it < 8; ++it) {
        const int kb0 = k0 + it * 64;
        LOADKV(B, kb0 + 32);         // 12 loads in flight...
        SBAR();                      // ...pinned above STEP(A)
        STEP(A, kb0);
        const int kbn = (it < 7) ? kb0 + 64 : k0;   // harmless reload on last
        LOADKV(A, kbn);              // 12 loads in flight...
        SBAR();                      // ...pinned above STEP(B)
        STEP(B, kb0 + 32);
    }

    // ---------- reduce denominators across the 4 k-quarter waves ----------
    lsum += __shfl_xor(lsum, 16, 64);
    lsum += __shfl_xor(lsum, 32, 64);
    if (lane < 16) s_red[w * 16 + l15] = lsum;
    __syncthreads();

    // ---------- combine partial P·V across waves; scale by 1/sum ----------
    s_acc[0 * 256 + w * 64 + lane] = acc0;
    s_acc[1 * 256 + w * 64 + lane] = acc1;
    s_acc[2 * 256 + w * 64 + lane] = acc2;
    s_acc[3 * 256 + w * 64 + lane] = acc3;
    __syncthreads();

    f32x4 t_ = s_acc[w * 256 + 0 * 64 + lane];
    #pragma unroll
    for (int wp = 1; wp < 4; wp++) {
        f32x4 u = s_acc[w * 256 + wp * 64 + lane];
        #pragma unroll
        for (int r = 0; r < 4; r++) t_[r] += u[r];
    }
    #pragma unroll
    for (int r = 0; r < 4; r++) {
        int rr = quad * 4 + r;
        float tt = s_red[rr] + s_red[16 + rr] + s_red[32 + rr] + s_red[48 + rr];
        out[(size_t)(b * SQL + qbase + rr) * DVL + w * 16 + l15] = t_[r] / tt;
    }
}

// ---------- norm: attn[row] /= sum(attn[row]), recomputing the sum ----------
// One block per row; masked entries are exactly 0 (exp2 underflow) so the
// recomputed sum equals the softmax denominator. No side buffer needed.
__global__ __launch_bounds__(256)
void norm(float* __restrict__ attn)
{
    __shared__ float sw[4];
    const int row = blockIdx.x;                  // 0 .. NB*SQL-1
    float* p = attn + (size_t)row * SKL + threadIdx.x * 8;
    f32x4 x0 = *(const f32x4*)p;
    f32x4 x1 = *(const f32x4*)(p + 4);
    float s = (x0[0] + x0[1]) + (x0[2] + x0[3])
            + (x1[0] + x1[1]) + (x1[2] + x1[3]);
    #pragma unroll
    for (int off = 1; off < 64; off <<= 1) s += __shfl_xor(s, off, 64);
    if ((threadIdx.x & 63) == 0) sw[threadIdx.x >> 6] = s;
    __syncthreads();
    const float inv = 1.0f / ((sw[0] + sw[1]) + (sw[2] + sw[3]));
    #pragma unroll
    for (int r = 0; r < 4; r++) { x0[r] *= inv; x1[r] *= inv; }
    *(f32x4*)p       = x0;
    *(f32x4*)(p + 4) = x1;
}

extern "C" void kernel_launch(void* const* d_in, const int* in_sizes, int n_in,
                              void* d_out, int out_size, void* d_ws, size_t ws_size,
                              hipStream_t stream) {
    const float* Q    = (const float*)d_in[0];
    const float* K    = (const float*)d_in[1];
    const float* V    = (const float*)d_in[2];
    const int*   mask = (const int*)d_in[3];
    float* out  = (float*)d_out;
    float* attn = out + (size_t)NB * SQL * DVL;  // tuple order: (output, attn)
    short* ws   = (short*)d_ws;                  // 5*NE shorts = 20 MB (unchanged)

    prep<<<dim3(NE / (256 * 4)), dim3(256), 0, stream>>>(Q, K, ws);
    vtrans<<<dim3(NB * (SKL / 64)), dim3(256), 0, stream>>>(V, ws + (size_t)4 * NE);
    attn_fwd<<<dim3(NB * (SQL / 16)), dim3(256), 0, stream>>>(ws, mask, out, attn);
    norm<<<dim3(NB * SQL), dim3(256), 0, stream>>>(attn);
}

// Round 9
// 448.755 us; speedup vs baseline: 1.1781x; 1.1781x over previous
//
#include <hip/hip_runtime.h>

#define NB   16
#define SQL  2048
#define SKL  2048
#define DKL  64
#define DVL  64
#define NE   (NB * SQL * DKL)   /* 2,097,152 elems per tensor */

typedef __attribute__((ext_vector_type(8))) short short8;
typedef __attribute__((ext_vector_type(4))) short s16x4;
typedef __attribute__((ext_vector_type(4))) float f32x4;
typedef __attribute__((ext_vector_type(4))) int   i32x4;
typedef __attribute__((ext_vector_type(4))) unsigned u32x4;

#define SCALE_LOG2E 0.1803368801111204f  /* (1/sqrt(64)) * log2(e) */
#define EXP2F(x) __builtin_amdgcn_exp2f(x)
#define MFMA32(a,b,c) __builtin_amdgcn_mfma_f32_16x16x32_bf16((a),(b),(c),0,0,0)

__device__ __forceinline__ short f2bf(float x) {  // rne f32 -> bf16 bits
    unsigned u = __builtin_bit_cast(unsigned, x);
    u = (u + 0x7fffu + ((u >> 16) & 1u)) >> 16;
    return (short)u;
}
__device__ __forceinline__ float bf2f(short s) {
    return __builtin_bit_cast(float, ((unsigned)(unsigned short)s) << 16);
}

// pack 8 f32 -> 8 bf16 (RNE) via v_cvt_pk_bf16_f32
__device__ __forceinline__ short8 pk8(f32x4 a, f32x4 b) {
    unsigned w0, w1, w2, w3;
    asm("v_cvt_pk_bf16_f32 %0, %1, %2" : "=v"(w0) : "v"(a[0]), "v"(a[1]));
    asm("v_cvt_pk_bf16_f32 %0, %1, %2" : "=v"(w1) : "v"(a[2]), "v"(a[3]));
    asm("v_cvt_pk_bf16_f32 %0, %1, %2" : "=v"(w2) : "v"(b[0]), "v"(b[1]));
    asm("v_cvt_pk_bf16_f32 %0, %1, %2" : "=v"(w3) : "v"(b[2]), "v"(b[3]));
    u32x4 t = {w0, w1, w2, w3};
    return __builtin_bit_cast(short8, t);
}

// ---------- prep: split Q,K into bf16 hi/lo ----------
__global__ __launch_bounds__(256)
void prep(const float* __restrict__ Q, const float* __restrict__ K,
          short* __restrict__ ws)
{
    short* qhi = ws;
    short* qlo = ws + (size_t)NE;
    short* khi = ws + (size_t)2 * NE;
    short* klo = ws + (size_t)3 * NE;

    size_t i4 = ((size_t)blockIdx.x * 256 + threadIdx.x) * 4;
    if (i4 >= NE) return;

    f32x4 q = *(const f32x4*)(Q + i4);
    f32x4 k = *(const f32x4*)(K + i4);
    s16x4 qh, ql, kh, kl;
    #pragma unroll
    for (int j = 0; j < 4; j++) {
        qh[j] = f2bf(q[j]);  ql[j] = f2bf(q[j] - bf2f(qh[j]));
        kh[j] = f2bf(k[j]);  kl[j] = f2bf(k[j] - bf2f(kh[j]));
    }
    *(s16x4*)(qhi + i4) = qh;
    *(s16x4*)(qlo + i4) = ql;
    *(s16x4*)(khi + i4) = kh;
    *(s16x4*)(klo + i4) = kl;
}

// ---------- vtrans: V fp32 [b][k][v] -> bf16 Vt, MFMA-slot-tiled ----------
// Vt[v][t*32 + quad*8 + jj] = V[t*32 + quad*4 + (jj&3) + 16*(jj>>2)][v]
// so a 16B load at (v*SKL + kb + quad*8) is the B-fragment matching the
// packed-P A-fragment slot order: ONE mfma_16x16x32 per v-tile per 32 keys.
__global__ __launch_bounds__(256)
void vtrans(const float* __restrict__ V, short* __restrict__ vt)
{
    __shared__ short st[64][72];          // 64x64 tile, padded stride
    const int b  = blockIdx.x >> 5;       // 32 k-tiles (of 64) per batch
    const int kt = blockIdx.x & 31;
    const int t  = threadIdx.x;

    const int kr = t >> 2;                // 0..63  (k row within tile)
    const int c0 = (t & 3) * 16;          // v col chunk
    const float* vsrc = V + ((size_t)(b * SKL) + kt * 64 + kr) * DVL + c0;
    #pragma unroll
    for (int j = 0; j < 4; j++) {
        f32x4 x = *(const f32x4*)(vsrc + j * 4);
        #pragma unroll
        for (int i = 0; i < 4; i++) st[kr][c0 + j * 4 + i] = f2bf(x[i]);
    }
    __syncthreads();

    const int vr = t >> 2;                // v row of output
    const int cc = (t & 3) * 16;          // 16-elem chunk within 64 keys
    short* dst = vt + (size_t)b * DVL * SKL + (size_t)vr * SKL + kt * 64 + cc;
    short o[16];
    #pragma unroll
    for (int m = 0; m < 16; m++) {
        int kk = cc + m;
        int tb = kk >> 5;
        int w5 = kk & 31;
        int qd = w5 >> 3;
        int jj = w5 & 7;
        int kl = tb * 32 + qd * 4 + (jj & 3) + ((jj >> 2) << 4);
        o[m] = st[kl][vr];
    }
    *(short8*)(dst)     = *(short8*)(o);
    *(short8*)(dst + 8) = *(short8*)(o + 8);
}

// Block = 32 q-rows, 4 waves x 512-key quarters. Per-iteration memory tax is
// ~constant across all structures tried (rounds 0-7: 670-965 cy/slot; store
// type, LDS-vs-reg, barriers, sched fences all null), so the lever is FEWER
// iteration slots: 2 q-groups share each 12-load K/V block -> wave-iters/CU
// halve (512->256) at equal total MFMA/exp/store work. Single K/V register
// set, no pipeline machinery (proven null in round 7, and it was the
// register-pressure risk in round 8's failed build).
__global__ __launch_bounds__(256, 2)
void attn_fwd(const short* __restrict__ ws, const int* __restrict__ mask,
              float* __restrict__ out, float* __restrict__ attn)
{
    __shared__ __align__(16) char smem[32768 + 512];
    f32x4* s_acc = (f32x4*)smem;                 // [tile 0..7][w*64+lane] (32 KB)
    float* s_red = (float*)(smem + 32768);       // [g][w*16+l15] (128 floats)

    const int tid  = threadIdx.x;
    const int w    = tid >> 6;                   // wave = k-quarter
    const int lane = tid & 63;
    const int l15  = tid & 15;
    const int quad = (tid & 63) >> 4;

    // bijective XCD swizzle: 1024 blocks, 128-block chunks per XCD
    const int bid = blockIdx.x;
    const int swz = (bid & 7) * 128 + (bid >> 3);
    const int b     = swz >> 6;
    const int qbase = (swz & 63) * 32;

    const int k0 = w * (SKL / 4);

    const short* qhi = ws + (size_t)(b * SQL + qbase) * DKL;
    const short* qlo = qhi + (size_t)NE;
    const short* khi = ws + (size_t)2 * NE + (size_t)b * SKL * DKL;
    const short* klo = khi + (size_t)NE;
    const short* vtg = ws + (size_t)4 * NE + (size_t)b * DVL * SKL;
    const int*   mk  = mask + b * SKL;

    // Q fragments: group 0 = rows qbase+l15, group 1 = rows qbase+16+l15
    short8 qa0h = *(const short8*)(qhi + (size_t)l15 * DKL + quad * 8);
    short8 qa1h = *(const short8*)(qhi + (size_t)l15 * DKL + 32 + quad * 8);
    short8 qa0l = *(const short8*)(qlo + (size_t)l15 * DKL + quad * 8);
    short8 qa1l = *(const short8*)(qlo + (size_t)l15 * DKL + 32 + quad * 8);
    short8 qb0h = *(const short8*)(qhi + (size_t)(16 + l15) * DKL + quad * 8);
    short8 qb1h = *(const short8*)(qhi + (size_t)(16 + l15) * DKL + 32 + quad * 8);
    short8 qb0l = *(const short8*)(qlo + (size_t)(16 + l15) * DKL + quad * 8);
    short8 qb1l = *(const short8*)(qlo + (size_t)(16 + l15) * DKL + 32 + quad * 8);

    f32x4 acc00 = {0.f,0.f,0.f,0.f}, acc01 = acc00, acc02 = acc00, acc03 = acc00;
    f32x4 acc10 = acc00, acc11 = acc00, acc12 = acc00, acc13 = acc00;
    float lsum0 = 0.f, lsum1 = 0.f;

    for (int it = 0; it < 16; ++it) {
        const int kb = k0 + it * 32;

        // ---- 12 K/V fragment loads (shared by both q-groups) ----
        size_t o0 = (size_t)(kb + l15) * DKL + quad * 8;
        size_t o1 = o0 + (size_t)16 * DKL;
        short8 h0l = *(const short8*)(khi + o0);
        short8 h0h = *(const short8*)(khi + o0 + 32);
        short8 h1l = *(const short8*)(khi + o1);
        short8 h1h = *(const short8*)(khi + o1 + 32);
        short8 l0l = *(const short8*)(klo + o0);
        short8 l0h = *(const short8*)(klo + o0 + 32);
        short8 l1l = *(const short8*)(klo + o1);
        short8 l1h = *(const short8*)(klo + o1 + 32);
        const short* vrow = vtg + kb + quad * 8;
        short8 vv0 = *(const short8*)(vrow + (size_t)(0 * 16 + l15) * SKL);
        short8 vv1 = *(const short8*)(vrow + (size_t)(1 * 16 + l15) * SKL);
        short8 vv2 = *(const short8*)(vrow + (size_t)(2 * 16 + l15) * SKL);
        short8 vv3 = *(const short8*)(vrow + (size_t)(3 * 16 + l15) * SKL);
        i32x4 m0 = *(const i32x4*)(mk + kb + quad * 4);
        i32x4 m1 = *(const i32x4*)(mk + kb + 16 + quad * 4);

        // ---- QK for both q-groups (split-bf16, 24 MFMA) ----
        f32x4 z = {0.f, 0.f, 0.f, 0.f};
        f32x4 sA0 = MFMA32(h0l, qa0h, z);
        sA0 = MFMA32(l0l, qa0h, sA0);
        sA0 = MFMA32(h0l, qa0l, sA0);
        f32x4 sB0 = MFMA32(h0h, qa1h, z);
        sB0 = MFMA32(l0h, qa1h, sB0);
        sB0 = MFMA32(h0h, qa1l, sB0);
        f32x4 sA1 = MFMA32(h1l, qa0h, z);
        sA1 = MFMA32(l1l, qa0h, sA1);
        sA1 = MFMA32(h1l, qa0l, sA1);
        f32x4 sB1 = MFMA32(h1h, qa1h, z);
        sB1 = MFMA32(l1h, qa1h, sB1);
        sB1 = MFMA32(h1h, qa1l, sB1);
        f32x4 tA0 = MFMA32(h0l, qb0h, z);
        tA0 = MFMA32(l0l, qb0h, tA0);
        tA0 = MFMA32(h0l, qb0l, tA0);
        f32x4 tB0 = MFMA32(h0h, qb1h, z);
        tB0 = MFMA32(l0h, qb1h, tB0);
        tB0 = MFMA32(h0h, qb1l, tB0);
        f32x4 tA1 = MFMA32(h1l, qb0h, z);
        tA1 = MFMA32(l1l, qb0h, tA1);
        tA1 = MFMA32(h1l, qb0l, tA1);
        f32x4 tB1 = MFMA32(h1h, qb1h, z);
        tB1 = MFMA32(l1h, qb1h, tB1);
        tB1 = MFMA32(h1h, qb1l, tB1);

        // ---- unnormalized P' = exp2(s*scale + bias); sums ----
        f32x4 p0, p1, q0, q1;
        #pragma unroll
        for (int r = 0; r < 4; r++) {
            float bias0 = m0[r] ? 0.f : -1e9f;
            float bias1 = m1[r] ? 0.f : -1e9f;
            p0[r] = EXP2F(fmaf(sA0[r] + sB0[r], SCALE_LOG2E, bias0));
            p1[r] = EXP2F(fmaf(sA1[r] + sB1[r], SCALE_LOG2E, bias1));
            q0[r] = EXP2F(fmaf(tA0[r] + tB0[r], SCALE_LOG2E, bias0));
            q1[r] = EXP2F(fmaf(tA1[r] + tB1[r], SCALE_LOG2E, bias1));
            lsum0 += p0[r] + p1[r];
            lsum1 += q0[r] + q1[r];
        }

        // ---- attn stores: coalesced dwordx4 (normalized later by `norm`) ----
        float* a0 = attn + (size_t)(b * SQL + qbase + l15) * SKL + kb + quad * 4;
        float* a1 = attn + (size_t)(b * SQL + qbase + 16 + l15) * SKL + kb + quad * 4;
        *(f32x4*)a0        = p0;
        *(f32x4*)(a0 + 16) = p1;
        *(f32x4*)a1        = q0;
        *(f32x4*)(a1 + 16) = q1;

        // ---- PV: packed P is the mfma A-fragment matching Vt's slot order ----
        short8 pa = pk8(p0, p1);
        short8 pb = pk8(q0, q1);
        acc00 = MFMA32(pa, vv0, acc00);
        acc01 = MFMA32(pa, vv1, acc01);
        acc02 = MFMA32(pa, vv2, acc02);
        acc03 = MFMA32(pa, vv3, acc03);
        acc10 = MFMA32(pb, vv0, acc10);
        acc11 = MFMA32(pb, vv1, acc11);
        acc12 = MFMA32(pb, vv2, acc12);
        acc13 = MFMA32(pb, vv3, acc13);
    }

    // ---------- reduce denominators across the 4 k-quarter waves ----------
    lsum0 += __shfl_xor(lsum0, 16, 64);
    lsum0 += __shfl_xor(lsum0, 32, 64);
    lsum1 += __shfl_xor(lsum1, 16, 64);
    lsum1 += __shfl_xor(lsum1, 32, 64);
    if (lane < 16) {
        s_red[w * 16 + l15]      = lsum0;
        s_red[64 + w * 16 + l15] = lsum1;
    }

    // ---------- combine partial P·V across waves; scale by 1/sum ----------
    s_acc[0 * 256 + w * 64 + lane] = acc00;
    s_acc[1 * 256 + w * 64 + lane] = acc01;
    s_acc[2 * 256 + w * 64 + lane] = acc02;
    s_acc[3 * 256 + w * 64 + lane] = acc03;
    s_acc[4 * 256 + w * 64 + lane] = acc10;
    s_acc[5 * 256 + w * 64 + lane] = acc11;
    s_acc[6 * 256 + w * 64 + lane] = acc12;
    s_acc[7 * 256 + w * 64 + lane] = acc13;
    __syncthreads();

    #pragma unroll
    for (int c = 0; c < 2; c++) {
        const int T  = w * 2 + c;            // this wave combines tiles 2w,2w+1
        const int g  = T >> 2;
        const int vt = T & 3;
        f32x4 t_ = s_acc[T * 256 + 0 * 64 + lane];
        #pragma unroll
        for (int wp = 1; wp < 4; wp++) {
            f32x4 u = s_acc[T * 256 + wp * 64 + lane];
            #pragma unroll
            for (int r = 0; r < 4; r++) t_[r] += u[r];
        }
        #pragma unroll
        for (int r = 0; r < 4; r++) {
            const int qr = quad * 4 + r;
            float tt = s_red[g * 64 + qr]      + s_red[g * 64 + 16 + qr]
                     + s_red[g * 64 + 32 + qr] + s_red[g * 64 + 48 + qr];
            out[(size_t)(b * SQL + qbase + g * 16 + qr) * DVL + vt * 16 + l15] =
                t_[r] / tt;
        }
    }
}

// ---------- norm: attn[row] /= sum(attn[row]), recomputing the sum ----------
// One block per row; masked entries are exactly 0 (exp2 underflow) so the
// recomputed sum equals the softmax denominator. No side buffer needed.
__global__ __launch_bounds__(256)
void norm(float* __restrict__ attn)
{
    __shared__ float sw[4];
    const int row = blockIdx.x;                  // 0 .. NB*SQL-1
    float* p = attn + (size_t)row * SKL + threadIdx.x * 8;
    f32x4 x0 = *(const f32x4*)p;
    f32x4 x1 = *(const f32x4*)(p + 4);
    float s = (x0[0] + x0[1]) + (x0[2] + x0[3])
            + (x1[0] + x1[1]) + (x1[2] + x1[3]);
    #pragma unroll
    for (int off = 1; off < 64; off <<= 1) s += __shfl_xor(s, off, 64);
    if ((threadIdx.x & 63) == 0) sw[threadIdx.x >> 6] = s;
    __syncthreads();
    const float inv = 1.0f / ((sw[0] + sw[1]) + (sw[2] + sw[3]));
    #pragma unroll
    for (int r = 0; r < 4; r++) { x0[r] *= inv; x1[r] *= inv; }
    *(f32x4*)p       = x0;
    *(f32x4*)(p + 4) = x1;
}

extern "C" void kernel_launch(void* const* d_in, const int* in_sizes, int n_in,
                              void* d_out, int out_size, void* d_ws, size_t ws_size,
                              hipStream_t stream) {
    const float* Q    = (const float*)d_in[0];
    const float* K    = (const float*)d_in[1];
    const float* V    = (const float*)d_in[2];
    const int*   mask = (const int*)d_in[3];
    float* out  = (float*)d_out;
    float* attn = out + (size_t)NB * SQL * DVL;  // tuple order: (output, attn)
    short* ws   = (short*)d_ws;                  // 5*NE shorts = 20 MB (unchanged)

    prep<<<dim3(NE / (256 * 4)), dim3(256), 0, stream>>>(Q, K, ws);
    vtrans<<<dim3(NB * (SKL / 64)), dim3(256), 0, stream>>>(V, ws + (size_t)4 * NE);
    attn_fwd<<<dim3(NB * (SQL / 32)), dim3(256), 0, stream>>>(ws, mask, out, attn);
    norm<<<dim3(NB * SQL), dim3(256), 0, stream>>>(attn);
}